// Round 2
// baseline (98.396 us; speedup 1.0000x reference)
//
#include <hip/hip_runtime.h>
#include <math.h>

#define N_TOT 4096
#define N_UPC 2048
#define HID 32
#define NC 16           // polynomial coeffs (degree 15) in w = 2*decay - 1
#define ITILE 256
#define JCH 64

// Monomial coefficients of G(w), where F(s) = decay * G(2*decay-1),
// decay = exp(1 - 1/(1 - clip(s/25))). One row per spin-pair table.
__device__ float g_coef[2][NC];

// Kernel 1: out = rs everywhere; block 0 additionally fits both polynomials.
// Fit: G(t) = bo + sum_k wo_k*swish(w1_k*t + b1_k) sampled at 16 Chebyshev
// nodes -> DCT -> Chebyshev coeffs -> monomial coeffs via T_n recurrence.
__global__ void fit_init_kernel(const float* __restrict__ rs,
    const float* __restrict__ sw1, const float* __restrict__ sb1,
    const float* __restrict__ swo, const float* __restrict__ sbo,
    const float* __restrict__ dw1, const float* __restrict__ db1,
    const float* __restrict__ dwo, const float* __restrict__ dbo,
    float* __restrict__ out) {
  int gtid = blockIdx.x * blockDim.x + threadIdx.x;
  if (gtid < 3 * N_TOT) out[gtid] = rs[gtid];
  if (blockIdx.x != 0) return;

  const int tid = threadIdx.x;
  const float PI = 3.14159265358979323846f;
  __shared__ float Gv[2][NC];   // G at nodes
  __shared__ float cb[2][NC];   // Chebyshev coeffs
  __shared__ float Tm2[NC], Tm1[NC], mono0[NC], mono1[NC];

  // 1) node evaluations: 32 threads (tab = tid>>4, node m = tid&15)
  if (tid < 2 * NC) {
    int tab = tid >> 4, m = tid & (NC - 1);
    const float* w1 = tab ? dw1 : sw1;
    const float* b1 = tab ? db1 : sb1;
    const float* wo = tab ? dwo : swo;
    float bo = tab ? dbo[0] : sbo[0];
    float um = cosf(PI * (m + 0.5f) / NC);   // node in u-space [-1,1]
    float t = 0.5f * (um + 1.0f);            // decay value in [0,1]
    float g = bo;
    for (int k = 0; k < HID; ++k) {
      float z = fmaf(t, w1[k], b1[k]);
      g = fmaf(z / (1.0f + expf(-z)), wo[k], g);  // swish
    }
    Gv[tab][m] = g;
  }
  __syncthreads();

  // 2) DCT -> Chebyshev coefficients
  if (tid < 2 * NC) {
    int tab = tid >> 4, j = tid & (NC - 1);
    float c = 0.0f;
    for (int m = 0; m < NC; ++m)
      c += Gv[tab][m] * cosf(PI * j * (m + 0.5f) / NC);
    c *= 2.0f / NC;
    if (j == 0) c *= 0.5f;
    cb[tab][j] = c;
  }
  __syncthreads();

  // 3) Chebyshev -> monomial: T_n[k] = 2*T_{n-1}[k-1] - T_{n-2}[k]
  if (tid < NC) {
    Tm2[tid] = (tid == 0) ? 1.0f : 0.0f;   // T_0
    Tm1[tid] = (tid == 1) ? 1.0f : 0.0f;   // T_1
    mono0[tid] = cb[0][0] * Tm2[tid] + cb[0][1] * Tm1[tid];
    mono1[tid] = cb[1][0] * Tm2[tid] + cb[1][1] * Tm1[tid];
  }
  __syncthreads();
  for (int n = 2; n < NC; ++n) {
    float tn = 0.0f;
    if (tid < NC) {
      float tkm1 = (tid >= 1) ? Tm1[tid - 1] : 0.0f;
      tn = 2.0f * tkm1 - Tm2[tid];
    }
    __syncthreads();                       // all reads done before overwrite
    if (tid < NC) {
      Tm2[tid] = Tm1[tid];
      Tm1[tid] = tn;
      mono0[tid] = fmaf(cb[0][n], tn, mono0[tid]);
      mono1[tid] = fmaf(cb[1][n], tn, mono1[tid]);
    }
    __syncthreads();
  }
  if (tid < NC) {
    g_coef[0][tid] = mono0[tid];
    g_coef[1][tid] = mono1[tid];
  }
}

// Kernel 2: 16 i-tiles x 64 j-chunks = 1024 blocks. Pure VALU, no LDS.
__global__ __launch_bounds__(256) void pair_kernel(const float* __restrict__ rs,
                                                   float* __restrict__ out) {
  int itile = blockIdx.x & 15;
  int jc = blockIdx.x >> 4;
  int i = itile * ITILE + threadIdx.x;
  float xi = rs[3 * i + 0];
  float yi = rs[3 * i + 1];
  float zi = rs[3 * i + 2];

  // spin(i) block-uniform; j-chunk entirely one spin
  const bool same_spin = ((jc < (N_UPC / JCH)) == (itile < 8));
  const float* __restrict__ cfp = g_coef[same_spin ? 0 : 1];
  float cf[NC];
#pragma unroll
  for (int k = 0; k < NC; ++k) cf[k] = cfp[k];

  float ax = 0.f, ay = 0.f, az = 0.f;
  int j0 = jc * JCH;
#pragma unroll 4
  for (int jj = 0; jj < JCH; ++jj) {
    int j = j0 + jj;
    float dx = xi - rs[3 * j + 0];   // wave-uniform addr -> scalar loads
    float dy = yi - rs[3 * j + 1];
    float dz = zi - rs[3 * j + 2];
    dx = fmaf(-10.0f, rintf(dx * 0.1f), dx);   // min-image
    dy = fmaf(-10.0f, rintf(dy * 0.1f), dy);
    dz = fmaf(-10.0f, rintf(dz * 0.1f), dz);
    float s = fmaf(dx, dx, fmaf(dy, dy, dz * dz));
    // decay = exp(1 - 1/(1-u)), u = clip(s/25, ., 1-2e-5); underflows to 0
    // exactly where the reference's decay underflows (r >~ 4.97)
    float u = fminf(s * 0.04f, 0.99998f);
    float r = __builtin_amdgcn_rcpf(1.0f - u);
    float t = __expf(1.0f - r);
    float w = fmaf(2.0f, t, -1.0f);
    float P = cf[NC - 1];
#pragma unroll
    for (int k = NC - 2; k >= 0; --k) P = fmaf(P, w, cf[k]);
    float F = t * P;                 // i==j: d=0 -> contribution 0
    ax = fmaf(F, dx, ax);
    ay = fmaf(F, dy, ay);
    az = fmaf(F, dz, az);
  }
  atomicAdd(&out[3 * i + 0], ax);
  atomicAdd(&out[3 * i + 1], ay);
  atomicAdd(&out[3 * i + 2], az);
}

extern "C" void kernel_launch(void* const* d_in, const int* in_sizes, int n_in,
                              void* d_out, int out_size, void* d_ws, size_t ws_size,
                              hipStream_t stream) {
  const float* rs = (const float*)d_in[0];
  fit_init_kernel<<<48, 256, 0, stream>>>(
      rs,
      (const float*)d_in[1], (const float*)d_in[2], (const float*)d_in[3],
      (const float*)d_in[4],
      (const float*)d_in[5], (const float*)d_in[6], (const float*)d_in[7],
      (const float*)d_in[8],
      (float*)d_out);
  pair_kernel<<<(N_TOT / ITILE) * (N_TOT / JCH), ITILE, 0, stream>>>(
      rs, (float*)d_out);
}

// Round 3
// 96.897 us; speedup vs baseline: 1.0155x; 1.0155x over previous
//
#include <hip/hip_runtime.h>
#include <math.h>

#define N_TOT 4096
#define N_UPC 2048
#define HID 32
#define NNODE 16        // Chebyshev sample nodes
#define NC 12           // polynomial coeffs kept (degree 11) in w = 2*decay - 1
#define ITILE 256
#define JCH 128

// Monomial coefficients of G(w), where F(s) = decay * G(2*decay-1),
// decay = exp(1 - 1/(1 - clip(s/25))). One row per spin-pair table.
__device__ float g_coef[2][NC];

// Kernel 1: out = rs everywhere; block 0 additionally fits both polynomials.
// G(t) = bo + sum_k wo_k*swish(w1_k*t + b1_k) sampled at 16 Chebyshev nodes
// -> DCT -> Chebyshev coeffs (truncated to NC) -> monomial via T_n recurrence.
__global__ void fit_init_kernel(const float* __restrict__ rs,
    const float* __restrict__ sw1, const float* __restrict__ sb1,
    const float* __restrict__ swo, const float* __restrict__ sbo,
    const float* __restrict__ dw1, const float* __restrict__ db1,
    const float* __restrict__ dwo, const float* __restrict__ dbo,
    float* __restrict__ out) {
  int gtid = blockIdx.x * blockDim.x + threadIdx.x;
  if (gtid < 3 * N_TOT) out[gtid] = rs[gtid];
  if (blockIdx.x != 0) return;

  const int tid = threadIdx.x;
  const float PI = 3.14159265358979323846f;
  __shared__ float Gv[2][NNODE];  // G at nodes
  __shared__ float cb[2][NC];     // Chebyshev coeffs
  __shared__ float Tm2[NC], Tm1[NC], mono0[NC], mono1[NC];

  // 1) node evaluations: 32 threads (tab = tid>>4, node m = tid&15)
  if (tid < 2 * NNODE) {
    int tab = tid >> 4, m = tid & (NNODE - 1);
    const float* w1 = tab ? dw1 : sw1;
    const float* b1 = tab ? db1 : sb1;
    const float* wo = tab ? dwo : swo;
    float bo = tab ? dbo[0] : sbo[0];
    float um = cosf(PI * (m + 0.5f) / NNODE);  // node in u-space [-1,1]
    float t = 0.5f * (um + 1.0f);              // decay value in [0,1]
    float g = bo;
    for (int k = 0; k < HID; ++k) {
      float z = fmaf(t, w1[k], b1[k]);
      g = fmaf(z / (1.0f + expf(-z)), wo[k], g);  // swish
    }
    Gv[tab][m] = g;
  }
  __syncthreads();

  // 2) DCT -> Chebyshev coefficients (keep first NC)
  if (tid < 2 * NC) {
    int tab = (tid >= NC), j = tab ? tid - NC : tid;
    float c = 0.0f;
    for (int m = 0; m < NNODE; ++m)
      c += Gv[tab][m] * cosf(PI * j * (m + 0.5f) / NNODE);
    c *= 2.0f / NNODE;
    if (j == 0) c *= 0.5f;
    cb[tab][j] = c;
  }
  __syncthreads();

  // 3) Chebyshev -> monomial: T_n[k] = 2*T_{n-1}[k-1] - T_{n-2}[k]
  if (tid < NC) {
    Tm2[tid] = (tid == 0) ? 1.0f : 0.0f;   // T_0
    Tm1[tid] = (tid == 1) ? 1.0f : 0.0f;   // T_1
    mono0[tid] = cb[0][0] * Tm2[tid] + cb[0][1] * Tm1[tid];
    mono1[tid] = cb[1][0] * Tm2[tid] + cb[1][1] * Tm1[tid];
  }
  __syncthreads();
  for (int n = 2; n < NC; ++n) {
    float tn = 0.0f;
    if (tid < NC) {
      float tkm1 = (tid >= 1) ? Tm1[tid - 1] : 0.0f;
      tn = 2.0f * tkm1 - Tm2[tid];
    }
    __syncthreads();                       // all reads done before overwrite
    if (tid < NC) {
      Tm2[tid] = Tm1[tid];
      Tm1[tid] = tn;
      mono0[tid] = fmaf(cb[0][n], tn, mono0[tid]);
      mono1[tid] = fmaf(cb[1][n], tn, mono1[tid]);
    }
    __syncthreads();
  }
  if (tid < NC) {
    g_coef[0][tid] = mono0[tid];
    g_coef[1][tid] = mono1[tid];
  }
}

// Kernel 2: 16 i-tiles x 32 j-chunks = 512 blocks (2/CU), 256 threads.
// Pure VALU, no LDS; atomics 32-way per address (halved vs JCH=64).
__global__ __launch_bounds__(256) void pair_kernel(const float* __restrict__ rs,
                                                   float* __restrict__ out) {
  int itile = blockIdx.x & 15;
  int jc = blockIdx.x >> 4;
  int i = itile * ITILE + threadIdx.x;
  float xi = rs[3 * i + 0];
  float yi = rs[3 * i + 1];
  float zi = rs[3 * i + 2];

  // spin(i) block-uniform; j-chunk entirely one spin
  const bool same_spin = ((jc < (N_UPC / JCH)) == (itile < 8));
  const float* __restrict__ cfp = g_coef[same_spin ? 0 : 1];
  float cf[NC];
#pragma unroll
  for (int k = 0; k < NC; ++k) cf[k] = cfp[k];

  float ax = 0.f, ay = 0.f, az = 0.f;
  int j0 = jc * JCH;
#pragma unroll 8
  for (int jj = 0; jj < JCH; ++jj) {
    int j = j0 + jj;
    float dx = xi - rs[3 * j + 0];   // wave-uniform addr -> scalar loads
    float dy = yi - rs[3 * j + 1];
    float dz = zi - rs[3 * j + 2];
    dx = fmaf(-10.0f, rintf(dx * 0.1f), dx);   // min-image
    dy = fmaf(-10.0f, rintf(dy * 0.1f), dy);
    dz = fmaf(-10.0f, rintf(dz * 0.1f), dz);
    float s = fmaf(dx, dx, fmaf(dy, dy, dz * dz));
    // decay = exp(1 - 1/(1-u)); underflows to 0 exactly where ref's does
    float u = fminf(s * 0.04f, 0.99998f);
    float r = __builtin_amdgcn_rcpf(1.0f - u);
    float t = __expf(1.0f - r);
    float w = fmaf(2.0f, t, -1.0f);
    float P = cf[NC - 1];
#pragma unroll
    for (int k = NC - 2; k >= 0; --k) P = fmaf(P, w, cf[k]);
    float F = t * P;                 // i==j: d=0 -> contribution 0
    ax = fmaf(F, dx, ax);
    ay = fmaf(F, dy, ay);
    az = fmaf(F, dz, az);
  }
  atomicAdd(&out[3 * i + 0], ax);
  atomicAdd(&out[3 * i + 1], ay);
  atomicAdd(&out[3 * i + 2], az);
}

extern "C" void kernel_launch(void* const* d_in, const int* in_sizes, int n_in,
                              void* d_out, int out_size, void* d_ws, size_t ws_size,
                              hipStream_t stream) {
  const float* rs = (const float*)d_in[0];
  fit_init_kernel<<<48, 256, 0, stream>>>(
      rs,
      (const float*)d_in[1], (const float*)d_in[2], (const float*)d_in[3],
      (const float*)d_in[4],
      (const float*)d_in[5], (const float*)d_in[6], (const float*)d_in[7],
      (const float*)d_in[8],
      (float*)d_out);
  pair_kernel<<<(N_TOT / ITILE) * (N_TOT / JCH), ITILE, 0, stream>>>(
      rs, (float*)d_out);
}

// Round 4
// 91.004 us; speedup vs baseline: 1.0812x; 1.0648x over previous
//
#include <hip/hip_runtime.h>
#include <math.h>

#define N_TOT 4096
#define N_UPC 2048
#define HID 32
#define M_LUT 2048
#define ITILE 256
#define JCH 128

// Entry m of table t: (F(s_m), F(s_{m+1})-F(s_m)), s_m = m * 25/(M_LUT-1).
// F(s) = decay * NN(decay), so F is a function of s alone per spin-pair type.
__device__ float2 g_lut[2 * M_LUT];

__device__ __forceinline__ float eval_F(float s, const float* __restrict__ w1,
                                        const float* __restrict__ b1,
                                        const float* __restrict__ wo, float bo) {
  // replicate reference numerics: r = sqrt(s+1e-15), xn = clip(r/5, 0, 1-1e-5)
  float r = sqrtf(s + 1e-15f);
  float xn = fminf(r * 0.2f, 1.0f - 1e-5f);
  float dcy = __expf(1.0f - 1.0f / (1.0f - xn * xn));
  float acc = bo;
#pragma unroll
  for (int k = 0; k < HID; ++k) {
    float z = fmaf(dcy, w1[k], b1[k]);
    float h = z / (1.0f + __expf(-z));  // swish
    acc = fmaf(h, wo[k], acc);
  }
  return acc * dcy;
}

// Kernel 1: build both LUTs and initialize out = rs. (fully parallel, ~0.3 us)
__global__ void lut_init_kernel(const float* __restrict__ rs,
    const float* __restrict__ sw1, const float* __restrict__ sb1,
    const float* __restrict__ swo, const float* __restrict__ sbo,
    const float* __restrict__ dw1, const float* __restrict__ db1,
    const float* __restrict__ dwo, const float* __restrict__ dbo,
    float* __restrict__ out) {
  const float DSF = 25.0f / (float)(M_LUT - 1);
  int t = blockIdx.x * blockDim.x + threadIdx.x;
  if (t < 2 * M_LUT) {
    int tab = t >> 11;           // M_LUT = 2048
    int m = t & (M_LUT - 1);
    const float* w1 = tab ? dw1 : sw1;
    const float* b1 = tab ? db1 : sb1;
    const float* wo = tab ? dwo : swo;
    float bo = tab ? dbo[0] : sbo[0];
    float s0 = m * DSF;
    float f0 = eval_F(s0, w1, b1, wo, bo);
    float f1 = eval_F(s0 + DSF, w1, b1, wo, bo);
    g_lut[t] = make_float2(f0, f1 - f0);
  }
  if (t < 3 * N_TOT) out[t] = rs[t];   // out starts at rs; pair kernel adds
}

// Kernel 2: 16 i-tiles x 32 j-chunks = 512 blocks (2/CU), 256 threads.
// LDS holds only the single table this block needs (spin is block-uniform).
__global__ __launch_bounds__(256) void pair_kernel(const float* __restrict__ rs,
                                                   float* __restrict__ out) {
  __shared__ float2 lut[M_LUT];        // 16 KB

  int itile = blockIdx.x & 15;         // 16 i-tiles of 256
  int jc = blockIdx.x >> 4;            // 32 j-chunks of 128
  const bool same_spin = ((jc < (N_UPC / JCH)) == (itile < 8));
  const float2* __restrict__ src = g_lut + (same_spin ? 0 : M_LUT);
  for (int t = threadIdx.x; t < M_LUT; t += ITILE) lut[t] = src[t];

  int i = itile * ITILE + threadIdx.x;
  float xi = rs[3 * i + 0];
  float yi = rs[3 * i + 1];
  float zi = rs[3 * i + 2];
  __syncthreads();

  const float INV_DS = (float)(M_LUT - 1) / 25.0f;

  float ax = 0.f, ay = 0.f, az = 0.f;
  int j0 = jc * JCH;
#pragma unroll 8
  for (int jj = 0; jj < JCH; ++jj) {
    int j = j0 + jj;
    float dx = xi - rs[3 * j + 0];     // wave-uniform addr -> scalar loads
    float dy = yi - rs[3 * j + 1];
    float dz = zi - rs[3 * j + 2];
    // min-image: d - 10*rint(d/10); differs from ref's mod only where F==0
    dx = fmaf(-10.0f, rintf(dx * 0.1f), dx);
    dy = fmaf(-10.0f, rintf(dy * 0.1f), dy);
    dz = fmaf(-10.0f, rintf(dz * 0.1f), dz);
    float s = fmaf(dx, dx, fmaf(dy, dy, dz * dz));
    float u = s * INV_DS;
    int idx = min((int)u, M_LUT - 2);  // s>=25 lands in the exactly-zero tail
    float w = u - (float)idx;          // w>1 only where entry is (0,0)
    float2 e = lut[idx];
    float F = fmaf(w, e.y, e.x);       // i==j: d=0 -> contribution 0
    ax = fmaf(F, dx, ax);
    ay = fmaf(F, dy, ay);
    az = fmaf(F, dz, az);
  }
  atomicAdd(&out[3 * i + 0], ax);
  atomicAdd(&out[3 * i + 1], ay);
  atomicAdd(&out[3 * i + 2], az);
}

extern "C" void kernel_launch(void* const* d_in, const int* in_sizes, int n_in,
                              void* d_out, int out_size, void* d_ws, size_t ws_size,
                              hipStream_t stream) {
  const float* rs = (const float*)d_in[0];
  lut_init_kernel<<<64, 256, 0, stream>>>(
      rs,
      (const float*)d_in[1], (const float*)d_in[2], (const float*)d_in[3],
      (const float*)d_in[4],
      (const float*)d_in[5], (const float*)d_in[6], (const float*)d_in[7],
      (const float*)d_in[8],
      (float*)d_out);
  pair_kernel<<<(N_TOT / ITILE) * (N_TOT / JCH), ITILE, 0, stream>>>(
      rs, (float*)d_out);
}

// Round 5
// 86.763 us; speedup vs baseline: 1.1341x; 1.0489x over previous
//
#include <hip/hip_runtime.h>
#include <math.h>

#define N_TOT 4096
#define N_UPC 2048
#define HID 32
#define M_LUT 2048
#define ROWS_PER_BLK 8     // 512 blocks, 256 thr = 8 rows x 32 lanes
#define LANES_PER_ROW 32

// Entry m of table t: (F(s_m), F(s_{m+1})-F(s_m)), s_m = m * 25/(M_LUT-1).
// F(s) = decay * NN(decay), so F is a function of s alone per spin-pair type.
__device__ float2 g_lut[2 * M_LUT];

__device__ __forceinline__ float eval_F(float s, const float* __restrict__ w1,
                                        const float* __restrict__ b1,
                                        const float* __restrict__ wo, float bo) {
  // replicate reference numerics: r = sqrt(s+1e-15), xn = clip(r/5, 0, 1-1e-5)
  float r = sqrtf(s + 1e-15f);
  float xn = fminf(r * 0.2f, 1.0f - 1e-5f);
  float dcy = __expf(1.0f - 1.0f / (1.0f - xn * xn));
  float acc = bo;
#pragma unroll
  for (int k = 0; k < HID; ++k) {
    float z = fmaf(dcy, w1[k], b1[k]);
    float h = z / (1.0f + __expf(-z));  // swish
    acc = fmaf(h, wo[k], acc);
  }
  return acc * dcy;
}

// Kernel 1: build both LUTs (no out-init needed anymore).
__global__ void lut_init_kernel(
    const float* __restrict__ sw1, const float* __restrict__ sb1,
    const float* __restrict__ swo, const float* __restrict__ sbo,
    const float* __restrict__ dw1, const float* __restrict__ db1,
    const float* __restrict__ dwo, const float* __restrict__ dbo) {
  const float DSF = 25.0f / (float)(M_LUT - 1);
  int t = blockIdx.x * blockDim.x + threadIdx.x;
  if (t < 2 * M_LUT) {
    int tab = t >> 11;           // M_LUT = 2048
    int m = t & (M_LUT - 1);
    const float* w1 = tab ? dw1 : sw1;
    const float* b1 = tab ? db1 : sb1;
    const float* wo = tab ? dwo : swo;
    float bo = tab ? dbo[0] : sbo[0];
    float s0 = m * DSF;
    float f0 = eval_F(s0, w1, b1, wo, bo);
    float f1 = eval_F(s0 + DSF, w1, b1, wo, bo);
    g_lut[t] = make_float2(f0, f1 - f0);
  }
}

// Kernel 2: 512 blocks x 256 threads. Block owns 8 consecutive rows
// (spin-uniform: 2048 % 8 == 0). 32 lanes per row, each lane covers 128 j's
// (coalesced per-lane loads, L1-resident). Shuffle-reduce -> plain store.
// No atomics anywhere.
__global__ __launch_bounds__(256) void pair_kernel(const float* __restrict__ rs,
                                                   float* __restrict__ out) {
  __shared__ float2 lut[2 * M_LUT];    // 32 KB, both tables
  {
    const float4* __restrict__ src = (const float4*)g_lut;
    float4* dst = (float4*)lut;
    for (int t = threadIdx.x; t < M_LUT; t += 256) dst[t] = src[t];
  }

  const int row_local = threadIdx.x >> 5;
  const int lane = threadIdx.x & 31;
  const int i = blockIdx.x * ROWS_PER_BLK + row_local;
  const float xi = rs[3 * i + 0];
  const float yi = rs[3 * i + 1];
  const float zi = rs[3 * i + 2];
  __syncthreads();

  const bool i_up = (i < N_UPC);       // block-uniform
  const float2* __restrict__ tabA = lut + (i_up ? 0 : M_LUT);  // j in [0,2048)
  const float2* __restrict__ tabB = lut + (i_up ? M_LUT : 0);  // j in [2048,4096)
  const float INV_DS = (float)(M_LUT - 1) / 25.0f;

  float ax = 0.f, ay = 0.f, az = 0.f;

#pragma unroll 2
  for (int half = 0; half < 2; ++half) {
    const float2* __restrict__ tab = half ? tabB : tabA;
    int jbase = half * N_UPC + lane;
#pragma unroll 8
    for (int jj = 0; jj < N_UPC / LANES_PER_ROW; ++jj) {
      int j = jbase + jj * LANES_PER_ROW;
      float dx = xi - rs[3 * j + 0];   // coalesced vector loads, L1 hits
      float dy = yi - rs[3 * j + 1];
      float dz = zi - rs[3 * j + 2];
      // min-image: d - 10*rint(d/10); differs from ref's mod only where F==0
      dx = fmaf(-10.0f, rintf(dx * 0.1f), dx);
      dy = fmaf(-10.0f, rintf(dy * 0.1f), dy);
      dz = fmaf(-10.0f, rintf(dz * 0.1f), dz);
      float s = fmaf(dx, dx, fmaf(dy, dy, dz * dz));
      float u = s * INV_DS;
      int idx = min((int)u, M_LUT - 2);  // s>=25 lands in exactly-zero tail
      float w = u - (float)idx;          // w>1 only where entry is (0,0)
      float2 e = tab[idx];
      float F = fmaf(w, e.y, e.x);       // i==j: d=0 -> contribution 0
      ax = fmaf(F, dx, ax);
      ay = fmaf(F, dy, ay);
      az = fmaf(F, dz, az);
    }
  }

  // reduce across the 32 lanes of this row
#pragma unroll
  for (int m = 16; m >= 1; m >>= 1) {
    ax += __shfl_xor(ax, m, 32);
    ay += __shfl_xor(ay, m, 32);
    az += __shfl_xor(az, m, 32);
  }
  if (lane == 0) {
    out[3 * i + 0] = xi + ax;
    out[3 * i + 1] = yi + ay;
    out[3 * i + 2] = zi + az;
  }
}

extern "C" void kernel_launch(void* const* d_in, const int* in_sizes, int n_in,
                              void* d_out, int out_size, void* d_ws, size_t ws_size,
                              hipStream_t stream) {
  const float* rs = (const float*)d_in[0];
  lut_init_kernel<<<16, 256, 0, stream>>>(
      (const float*)d_in[1], (const float*)d_in[2], (const float*)d_in[3],
      (const float*)d_in[4],
      (const float*)d_in[5], (const float*)d_in[6], (const float*)d_in[7],
      (const float*)d_in[8]);
  pair_kernel<<<N_TOT / ROWS_PER_BLK, 256, 0, stream>>>(rs, (float*)d_out);
}